// Round 3
// baseline (56.216 us; speedup 1.0000x reference)
//
#include <hip/hip_runtime.h>
#include <math.h>

#define KPTS 512
#define VOX (64*64*64)
#define NBLK 4096            // 16x16x16 NMS blocks per instance
#define SLOTS 4              // deterministic winner slots per NMS block
#define NCAND (NBLK * SLOTS) // 16384
#define NSEL 1024

typedef unsigned long long u64;
typedef unsigned int u32;

typedef float f2v __attribute__((ext_vector_type(2)));
typedef f2v f2a __attribute__((aligned(4)));   // 8B vector load at 4B alignment

// f32 op-sequence sigmoid with correctly-rounded expf (via double):
// t = rn(exp(-x)); s = 1/(1+t)  -- mimics NumPy f32 semantics.
__device__ __forceinline__ float ref_sigmoid(float x) {
  float t = (float)exp(-(double)x);
  float d = 1.0f + t;
  return 1.0f / d;
}

// 256-thread strip: full x-rows (coalesced), y in [4yb,4yb+4), z in [4zb,4zb+4).
// Covers 16 NMS blocks (x-blocks). Winners written to fixed per-block slots;
// unused slots zeroed every call (no global atomics, no zeroing prepass).
__global__ void __launch_bounds__(256) nms_cand(const float* __restrict__ k1,
                                                const float* __restrict__ k2,
                                                u64* __restrict__ cands) {
  int strip = blockIdx.x;        // 0..255: yb = strip&15, zb = strip>>4
  int inst = blockIdx.y;         // m = inst>>1, b = inst&1
  const float* vol = ((inst >> 1) ? k2 : k1) + (size_t)(inst & 1) * VOX;
  int t = threadIdx.x;
  int x = t & 63, yl = t >> 6;
  int yb = strip & 15, zb = strip >> 4;
  int y = yb * 4 + yl, z0 = zb * 4;
  float s[4];
  #pragma unroll
  for (int zl = 0; zl < 4; zl++)
    s[zl] = ref_sigmoid(vol[((z0 + zl) << 12) | (y << 6) | x]);
  float m = fmaxf(fmaxf(s[0], s[1]), fmaxf(s[2], s[3]));
  m = fmaxf(m, __shfl_xor(m, 1));
  m = fmaxf(m, __shfl_xor(m, 2));          // max over 4x * 1y * 4z
  __shared__ float sm[4][16];
  __shared__ u32 wcnt[16];
  if (t < 16) wcnt[t] = 0;
  if ((x & 3) == 0) sm[yl][x >> 2] = m;
  __syncthreads();
  int xb = x >> 2;
  float bm = fmaxf(fmaxf(sm[0][xb], sm[1][xb]), fmaxf(sm[2][xb], sm[3][xb]));
  int nb = ((zb * 16 + yb) << 4) | xb;
  u64* slot = cands + (size_t)inst * NCAND + (size_t)nb * SLOTS;
  #pragma unroll
  for (int zl = 0; zl < 4; zl++) {
    if (s[zl] == bm) {                     // winner (ties all emitted)
      u32 r = atomicAdd(&wcnt[xb], 1u);    // LDS atomic, ~1 winner/block
      if (r < SLOTS) {
        int addr = ((z0 + zl) << 12) | (y << 6) | x;
        slot[r] = ((u64)__float_as_uint(s[zl]) << 32) | (u64)(0xFFFFFFFFu - (u32)addr);
      }
    }
  }
  __syncthreads();
  if (t < 16 * SLOTS) {                    // zero unused slots (every call)
    int xb2 = t >> 2, k = t & 3;
    if ((u32)k >= wcnt[xb2])
      cands[(size_t)inst * NCAND + (size_t)(((zb * 16 + yb) << 4) | xb2) * SLOTS + k] = 0;
  }
}

// Per instance: histogram-prune 16384 slot keys (zeros skipped) to >=512
// largest, bitonic-sort 1024 by (value desc, index asc), emit top 512.
__global__ void __launch_bounds__(1024) topk_sel(
    const u64* __restrict__ cands, int* __restrict__ pts, float* __restrict__ out) {
  __shared__ u32 hist[256];
  __shared__ u64 sel[NSEL];
  __shared__ u32 selCnt;
  __shared__ int bstar;
  int inst = blockIdx.x, tid = threadIdx.x;
  if (tid < 256) hist[tid] = 0;
  if (tid == 0) selCnt = 0;
  __syncthreads();
  const u64* cb = cands + (size_t)inst * NCAND;
  // 256 value-ordered bins: sigmoid in [0.5,1) -> mantissa bits [22:15]
  for (u32 i = tid; i < NCAND; i += 1024) {
    u64 key = cb[i];
    if (!key) continue;
    u32 vb = (u32)(key >> 32);
    int bin = (vb >= 0x3F800000u) ? 255 : ((vb < 0x3F000000u) ? 0 : (int)((vb >> 15) & 0xFF));
    atomicAdd(&hist[bin], 1u);
  }
  __syncthreads();
  if (tid == 0) {
    u32 cum = 0; int b = 255;
    for (; b >= 0; b--) { cum += hist[b]; if (cum >= KPTS) break; }
    bstar = (b < 0) ? 0 : b;
  }
  __syncthreads();
  int B = bstar;
  for (u32 i = tid; i < NCAND; i += 1024) {
    u64 key = cb[i];
    if (!key) continue;
    u32 vb = (u32)(key >> 32);
    int bin = (vb >= 0x3F800000u) ? 255 : ((vb < 0x3F000000u) ? 0 : (int)((vb >> 15) & 0xFF));
    if (bin >= B) {
      u32 p = atomicAdd(&selCnt, 1u);
      if (p < NSEL) sel[p] = key;
    }
  }
  __syncthreads();
  u32 sc = selCnt; if (sc > NSEL) sc = NSEL;
  for (int i = tid; i < NSEL; i += 1024) if (i >= (int)sc) sel[i] = 0ull;
  __syncthreads();
  // bitonic sort, descending; keys unique (idx distinct) -> deterministic
  for (int k = 2; k <= NSEL; k <<= 1) {
    for (int j = k >> 1; j > 0; j >>= 1) {
      int i = tid, l = tid ^ j;
      if (i < NSEL && l > i) {
        u64 a = sel[i], b2 = sel[l];
        bool desc = ((i & k) == 0);
        if (desc ? (a < b2) : (a > b2)) { sel[i] = b2; sel[l] = a; }
      }
      __syncthreads();
    }
  }
  if (tid < KPTS) {
    u32 idx = ~(u32)(sel[tid]);           // 0xFFFFFFFF - low
    pts[inst * KPTS + tid] = (int)idx;
    int x = idx & 63, y = (idx >> 6) & 63, z = (int)(idx >> 12);
    float gx = ((float)x * 2.0f) / 63.0f - 1.0f;
    float gy = ((float)y * 2.0f) / 63.0f - 1.0f;
    float gz = ((float)z * 2.0f) / 63.0f - 1.0f;
    int m = inst >> 1, b = inst & 1;
    float* g = out + (size_t)m * 3072 + (size_t)(b * KPTS + tid) * 3;
    g[0] = gx; g[1] = gy; g[2] = gz;
  }
}

// One wave per (instance, point); lane = channel. Trilinear sample via 4
// float2 row-loads per lane; kpt-map rows spread over lanes 0-3. Writes desc
// transposed [inst][kp][ch] so wave stores are 256B contiguous.
__global__ void __launch_bounds__(64) sample_kernel(
    const float* __restrict__ k1, const float* __restrict__ k2,
    const float* __restrict__ f1, const float* __restrict__ f2,
    const int* __restrict__ pts, float* __restrict__ desc,
    float* __restrict__ norms, float* __restrict__ out) {
  int bid = blockIdx.x;
  int inst = bid >> 9, kp = bid & 511;
  int m = inst >> 1, b = inst & 1;
  int lane = threadIdx.x;   // channel 0..63
  int idx = pts[inst * KPTS + kp];
  int x = idx & 63, y = (idx >> 6) & 63, z = idx >> 12;
  float gx = ((float)x * 2.0f) / 63.0f - 1.0f;
  float gy = ((float)y * 2.0f) / 63.0f - 1.0f;
  float gz = ((float)z * 2.0f) / 63.0f - 1.0f;
  float ix = ((gx + 1.0f) * 64.0f - 1.0f) * 0.5f;
  float iy = ((gy + 1.0f) * 64.0f - 1.0f) * 0.5f;
  float iz = ((gz + 1.0f) * 64.0f - 1.0f) * 0.5f;
  float x0f = floorf(ix), y0f = floorf(iy), z0f = floorf(iz);
  float fx = ix - x0f, fy = iy - y0f, fz = iz - z0f;
  int x0 = (int)x0f, y0 = (int)y0f, z0 = (int)z0f;
  // x handled via one float2 load per row: xc in [0,62]; select/mask
  int xc = x0 < 0 ? 0 : (x0 > 62 ? 62 : x0);
  bool xlo = (x0 == xc);
  float wx0 = (x0 >= 0) ? (1.0f - fx) : 0.0f;
  float wx1 = (x0 <= 62) ? fx : 0.0f;          // x1 = x0+1 <= 63
  int yc0 = y0 < 0 ? 0 : y0, yc1 = (y0 + 1) > 63 ? 63 : (y0 + 1);
  int zc0 = z0 < 0 ? 0 : z0, zc1 = (z0 + 1) > 63 ? 63 : (z0 + 1);
  float wy0 = (y0 >= 0) ? (1.0f - fy) : 0.0f;
  float wy1 = ((y0 + 1) <= 63) ? fy : 0.0f;
  float wz0 = (z0 >= 0) ? (1.0f - fz) : 0.0f;
  float wz1 = ((z0 + 1) <= 63) ? fz : 0.0f;

  const float* fv = (m ? f2 : f1) + ((size_t)b * 64 + lane) * VOX;
  float acc = 0.0f;
  #pragma unroll
  for (int dz = 0; dz < 2; dz++) {
    int zz = dz ? zc1 : zc0; float wzz = dz ? wz1 : wz0;
    #pragma unroll
    for (int dy = 0; dy < 2; dy++) {
      int yy = dy ? yc1 : yc0; float wyy = dy ? wy1 : wy0;
      f2a v = *reinterpret_cast<const f2a*>(fv + ((zz << 12) | (yy << 6) | xc));
      float v0 = xlo ? v.x : v.y;
      float v1 = xlo ? v.y : v.x;
      acc = fmaf(wzz * wyy, fmaf(v0, wx0, v1 * wx1), acc);
    }
  }
  desc[((size_t)inst * KPTS + kp) * 64 + lane] = acc;   // coalesced
  float ss = acc * acc;
  #pragma unroll
  for (int o = 32; o; o >>= 1) ss += __shfl_xor(ss, o);
  // kpt-map logit: 4 rows on lanes 0-3
  const float* kv = (m ? k2 : k1) + (size_t)b * VOX;
  float part = 0.0f;
  if (lane < 4) {
    int dz = lane >> 1, dy = lane & 1;
    int zz = dz ? zc1 : zc0; float wzz = dz ? wz1 : wz0;
    int yy = dy ? yc1 : yc0; float wyy = dy ? wy1 : wy0;
    f2a v = *reinterpret_cast<const f2a*>(kv + ((zz << 12) | (yy << 6) | xc));
    float v0 = xlo ? v.x : v.y;
    float v1 = xlo ? v.y : v.x;
    part = wzz * wyy * fmaf(v0, wx0, v1 * wx1);
  }
  part += __shfl_xor(part, 1);
  part += __shfl_xor(part, 2);
  if (lane == 0) {
    norms[inst * KPTS + kp] = sqrtf(ss);
    out[6144 + m * 1024 + b * KPTS + kp] = part;
  }
}

// 32x32 (i,j) tile per block. desc is [inst][kp][ch]. Pre-scaled e0=d1*w0,
// e1=d1*w1 in padded LDS (broadcast b128 reads); d2 row in 64 VGPRs.
// scores = e·d2 + bias; desc_norm = n1_i*|1/(1e-6+n1_i)-1/(1e-6+n2_j)|
// (both numerators are d1 in the reference).
__global__ void __launch_bounds__(256) matcher(const float* __restrict__ desc,
                                               const float* __restrict__ norms,
                                               const float* __restrict__ fc_w,
                                               const float* __restrict__ fc_b,
                                               float* __restrict__ out) {
  int bid = blockIdx.x;
  int b = bid >> 8, ti = (bid >> 4) & 15, tj = bid & 15;
  int i0 = ti * 32, j0 = tj * 32;
  __shared__ float e0t[32][68];
  __shared__ float e1t[32][68];
  __shared__ float n1s[32], n2s[32];
  int tid = threadIdx.x;
  const float* d1 = desc + (size_t)b * KPTS * 64;
  const float* d2 = desc + (size_t)(2 + b) * KPTS * 64;
  // stage e0/e1: thread t -> row t>>3, 8 channels at ci=(t&7)*8
  {
    int row = tid >> 3, ci = (tid & 7) * 8;
    const float4* dp = (const float4*)(d1 + (size_t)(i0 + row) * 64 + ci);
    const float4* wp0 = (const float4*)(fc_w + ci);
    const float4* wp1 = (const float4*)(fc_w + 64 + ci);
    float4 va = dp[0], vb = dp[1];
    float4 w0a = wp0[0], w0b = wp0[1], w1a = wp1[0], w1b = wp1[1];
    float4* e0p = (float4*)&e0t[row][ci];
    float4* e1p = (float4*)&e1t[row][ci];
    e0p[0] = make_float4(va.x * w0a.x, va.y * w0a.y, va.z * w0a.z, va.w * w0a.w);
    e0p[1] = make_float4(vb.x * w0b.x, vb.y * w0b.y, vb.z * w0b.z, vb.w * w0b.w);
    e1p[0] = make_float4(va.x * w1a.x, va.y * w1a.y, va.z * w1a.z, va.w * w1a.w);
    e1p[1] = make_float4(vb.x * w1b.x, vb.y * w1b.y, vb.z * w1b.z, vb.w * w1b.w);
  }
  if (tid < 32) n1s[tid] = norms[b * KPTS + i0 + tid];
  else if (tid < 64) n2s[tid - 32] = norms[(2 + b) * KPTS + j0 + (tid - 32)];
  // d2 row into registers (redundant x8 across r0, L1-hit)
  int j = tid & 31, r0 = tid >> 5;
  float4 d2r[16];
  const float* drow = d2 + (size_t)(j0 + j) * 64;
  #pragma unroll
  for (int q = 0; q < 16; q++) d2r[q] = *(const float4*)(drow + q * 4);
  __syncthreads();
  float bb0 = fc_b[0], bb1 = fc_b[1];
  float n2 = n2s[j];
  #pragma unroll
  for (int r = 0; r < 4; r++) {
    int i = r0 + r * 8;
    float s0 = 0.0f, s1 = 0.0f;
    #pragma unroll
    for (int q = 0; q < 16; q++) {
      float4 E0 = *(const float4*)&e0t[i][q * 4];
      float4 E1 = *(const float4*)&e1t[i][q * 4];
      float4 D = d2r[q];
      s0 = fmaf(E0.x, D.x, s0); s0 = fmaf(E0.y, D.y, s0);
      s0 = fmaf(E0.z, D.z, s0); s0 = fmaf(E0.w, D.w, s0);
      s1 = fmaf(E1.x, D.x, s1); s1 = fmaf(E1.y, D.y, s1);
      s1 = fmaf(E1.z, D.z, s1); s1 = fmaf(E1.w, D.w, s1);
    }
    int gi = i0 + i, gj = j0 + j;
    size_t row = ((size_t)(b * KPTS + gi)) * KPTS + gj;
    *(float2*)(out + 8192 + row * 2) = make_float2(s0 + bb0, s1 + bb1);
    float n1 = n1s[i];
    out[1056768 + row] = n1 * fabsf(1.0f / (1e-6f + n1) - 1.0f / (1e-6f + n2));
  }
}

extern "C" void kernel_launch(void* const* d_in, const int* in_sizes, int n_in,
                              void* d_out, int out_size, void* d_ws, size_t ws_size,
                              hipStream_t stream) {
  const float* k1 = (const float*)d_in[0];
  const float* k2 = (const float*)d_in[1];
  const float* f1 = (const float*)d_in[2];
  const float* f2 = (const float*)d_in[3];
  const float* fw = (const float*)d_in[4];
  const float* fb = (const float*)d_in[5];
  float* out = (float*)d_out;
  char* ws = (char*)d_ws;
  // ws: cands(4*16384*8B=512KB) | pts(8KB) | norms(8KB) | desc(4*512*64*4B=512KB)
  u64* cands   = (u64*)ws;
  int* pts     = (int*)(ws + 524288);
  float* norms = (float*)(ws + 524288 + 8192);
  float* desc  = (float*)(ws + 524288 + 8192 + 8192);

  hipLaunchKernelGGL(nms_cand, dim3(256, 4), dim3(256), 0, stream, k1, k2, cands);
  hipLaunchKernelGGL(topk_sel, dim3(4), dim3(1024), 0, stream, cands, pts, out);
  hipLaunchKernelGGL(sample_kernel, dim3(2048), dim3(64), 0, stream, k1, k2, f1, f2, pts, desc, norms, out);
  hipLaunchKernelGGL(matcher, dim3(512), dim3(256), 0, stream, desc, norms, fw, fb, out);
}